// Round 1
// baseline (1455.974 us; speedup 1.0000x reference)
//
#include <hip/hip_runtime.h>
#include <math.h>

namespace {
constexpr int NN = 100000;   // nodes
constexpr int NE = 1000000;  // edges
constexpr int D  = 64;       // feature dim (in = hid = 64)

__global__ void count_deg_k(const int* __restrict__ rows, int* __restrict__ deg, int e) {
    int i = blockIdx.x * blockDim.x + threadIdx.x;
    if (i < e) atomicAdd(&deg[rows[i]], 1);
}

__global__ void dis_k(const int* __restrict__ deg, float* __restrict__ dis, int n) {
    int i = blockIdx.x * blockDim.x + threadIdx.x;
    if (i < n) dis[i] = rsqrtf((float)(deg[i] + 1));  // +1 self-loop; always > 0
}

// [n,64] @ [64,64] -> [n,64]; W staged in LDS; 4 rows per 256-thread block.
__global__ void gemm64_k(const float* __restrict__ in, const float* __restrict__ W,
                         float* __restrict__ out, int n) {
    __shared__ float sW[D * D];
    for (int i = threadIdx.x; i < D * D; i += blockDim.x) sW[i] = W[i];
    __syncthreads();
    int r = blockIdx.x * (blockDim.x / D) + (threadIdx.x / D);
    int c = threadIdx.x & (D - 1);
    if (r >= n) return;
    const float* xr = in + (size_t)r * D;
    float acc = 0.f;
#pragma unroll
    for (int k = 0; k < D; ++k) acc = fmaf(xr[k], sW[k * D + c], acc);
    out[(size_t)r * D + c] = acc;
}

// out[r][f] = b[f] (bias pre-load so scatter accumulates on top of it)
__global__ void init_bias_k(float* __restrict__ out, const float* __restrict__ b, size_t total) {
    size_t i = (size_t)blockIdx.x * blockDim.x + threadIdx.x;
    if (i < total) out[i] = b[i & (D - 1)];
}

// One wave per (edge or self-loop). lane = feature. Broadcast index loads,
// coalesced 256B gather, coalesced 256B atomic scatter.
__global__ void scatter_k(const int* __restrict__ erows, const int* __restrict__ ecols,
                          const int* __restrict__ perm, const float* __restrict__ dis,
                          const float* __restrict__ src, float* __restrict__ dst,
                          int e, int n) {
    int lane = threadIdx.x & (D - 1);
    long long wave = ((long long)blockIdx.x * blockDim.x + threadIdx.x) >> 6;
    long long total = (long long)e + n;
    if (wave >= total) return;
    int r, c;
    if (wave < e) { r = erows[wave]; c = ecols[wave]; }
    else          { r = (int)(wave - e); c = r; }       // self-loop
    float norm = dis[r] * dis[c];
    int cs = perm ? perm[c] : c;                         // feature corruption = permuted gather
    float v = src[(size_t)cs * D + lane] * norm;
    atomicAdd(&dst[(size_t)r * D + lane], v);
}

__global__ void prelu_k(float* __restrict__ h, const float* __restrict__ a_p, size_t total) {
    size_t i = (size_t)blockIdx.x * blockDim.x + threadIdx.x;
    if (i < total) {
        float v = h[i];
        h[i] = v >= 0.f ? v : (*a_p) * v;
    }
}

// column sums of positive -> acc[64] (one atomic per lane per wave)
__global__ void summary_partial_k(const float* __restrict__ pos, float* __restrict__ acc, int n) {
    int lane = threadIdx.x & (D - 1);
    int wave = (blockIdx.x * blockDim.x + threadIdx.x) >> 6;
    int nw = (gridDim.x * blockDim.x) >> 6;
    float s = 0.f;
    for (int r = wave; r < n; r += nw) s += pos[(size_t)r * D + lane];
    atomicAdd(&acc[lane], s);
}

__global__ void summary_final_k(const float* __restrict__ acc, float* __restrict__ out, int n) {
    int f = threadIdx.x;
    if (f < D) {
        float m = acc[f] / (float)n;
        out[f] = 1.f / (1.f + expf(-m));
    }
}
} // namespace

extern "C" void kernel_launch(void* const* d_in, const int* in_sizes, int n_in,
                              void* d_out, int out_size, void* d_ws, size_t ws_size,
                              hipStream_t stream) {
    (void)in_sizes; (void)n_in; (void)out_size; (void)ws_size;
    const float* x       = (const float*)d_in[0];
    const int*   ei      = (const int*)  d_in[1];   // [2, E] row-major
    const int*   perm    = (const int*)  d_in[2];
    const float* W1      = (const float*)d_in[3];
    const float* b1      = (const float*)d_in[4];
    const float* prelu_a = (const float*)d_in[5];
    const float* W2      = (const float*)d_in[6];
    const float* b2      = (const float*)d_in[7];

    float* outP = (float*)d_out;                    // positive [N,64]
    float* outN = outP + (size_t)NN * D;            // negative [N,64]
    float* outS = outN + (size_t)NN * D;            // summary  [64]

    const int* erows = ei;        // edge_index[0]
    const int* ecols = ei + NE;   // edge_index[1]

    // workspace carve-up (poisoned 0xAA each call -> zero/overwrite everything we read)
    char* ws = (char*)d_ws;
    size_t off = 0;
    auto alloc = [&](size_t bytes) {
        void* p = ws + off;
        off = (off + bytes + 255) & ~(size_t)255;
        return p;
    };
    int*   deg  = (int*)  alloc((size_t)NN * 4);
    float* dis  = (float*)alloc((size_t)NN * 4);
    float* xw   = (float*)alloc((size_t)NN * D * 4);
    float* aggP = (float*)alloc((size_t)NN * D * 4);
    float* aggN = (float*)alloc((size_t)NN * D * 4);
    float* acc  = (float*)alloc((size_t)D * 4);
    // total ~77.6 MB

    hipMemsetAsync(deg, 0, (size_t)NN * 4, stream);
    hipMemsetAsync(acc, 0, (size_t)D * 4, stream);

    count_deg_k<<<(NE + 255) / 256, 256, 0, stream>>>(erows, deg, NE);
    dis_k<<<(NN + 255) / 256, 256, 0, stream>>>(deg, dis, NN);

    const int gemmBlocks = (NN + 3) / 4;
    const size_t tot = (size_t)NN * D;
    const int elemBlocks = (int)((tot + 255) / 256);
    const long long scatterThreads = (long long)(NE + NN) * D;
    const int scatterBlocks = (int)((scatterThreads + 255) / 256);

    // layer 1: xw = x @ W1 once; negative branch permutes the gather index
    gemm64_k<<<gemmBlocks, 256, 0, stream>>>(x, W1, xw, NN);

    init_bias_k<<<elemBlocks, 256, 0, stream>>>(aggP, b1, tot);
    scatter_k<<<scatterBlocks, 256, 0, stream>>>(erows, ecols, nullptr, dis, xw, aggP, NE, NN);
    init_bias_k<<<elemBlocks, 256, 0, stream>>>(aggN, b1, tot);
    scatter_k<<<scatterBlocks, 256, 0, stream>>>(erows, ecols, perm, dis, xw, aggN, NE, NN);

    prelu_k<<<elemBlocks, 256, 0, stream>>>(aggP, prelu_a, tot);
    prelu_k<<<elemBlocks, 256, 0, stream>>>(aggN, prelu_a, tot);

    // layer 2 positive
    gemm64_k<<<gemmBlocks, 256, 0, stream>>>(aggP, W2, xw, NN);
    init_bias_k<<<elemBlocks, 256, 0, stream>>>(outP, b2, tot);
    scatter_k<<<scatterBlocks, 256, 0, stream>>>(erows, ecols, nullptr, dis, xw, outP, NE, NN);

    // layer 2 negative
    gemm64_k<<<gemmBlocks, 256, 0, stream>>>(aggN, W2, xw, NN);
    init_bias_k<<<elemBlocks, 256, 0, stream>>>(outN, b2, tot);
    scatter_k<<<scatterBlocks, 256, 0, stream>>>(erows, ecols, nullptr, dis, xw, outN, NE, NN);

    // summary = sigmoid(mean(positive, axis=0))
    summary_partial_k<<<256, 256, 0, stream>>>(outP, acc, NN);
    summary_final_k<<<1, 64, 0, stream>>>(acc, outS, NN);
}

// Round 2
// 870.688 us; speedup vs baseline: 1.6722x; 1.6722x over previous
//
#include <hip/hip_runtime.h>
#include <math.h>

namespace {
constexpr int NN = 100000;   // nodes
constexpr int NE = 1000000;  // edges
constexpr int D  = 64;       // feature dim

__global__ void count_deg_k(const int* __restrict__ rows, int* __restrict__ deg, int e) {
    int i = blockIdx.x * blockDim.x + threadIdx.x;
    if (i < e) atomicAdd(&deg[rows[i]], 1);
}

__global__ void dis_k(const int* __restrict__ deg, float* __restrict__ dis, int n) {
    int i = blockIdx.x * blockDim.x + threadIdx.x;
    if (i < n) dis[i] = rsqrtf((float)(deg[i] + 1));  // +1 self-loop
}

// single-block chunked Hillis-Steele exclusive scan of deg -> rowstart
__global__ void scan_k(const int* __restrict__ deg, int* __restrict__ rowstart, int n) {
    __shared__ int smem[1024];
    __shared__ int running;
    if (threadIdx.x == 0) running = 0;
    __syncthreads();
    for (int base = 0; base < n; base += 1024) {
        int i = base + (int)threadIdx.x;
        int v = (i < n) ? deg[i] : 0;
        smem[threadIdx.x] = v;
        __syncthreads();
        for (int off = 1; off < 1024; off <<= 1) {
            int t = (threadIdx.x >= (unsigned)off) ? smem[threadIdx.x - off] : 0;
            __syncthreads();
            smem[threadIdx.x] += t;
            __syncthreads();
        }
        if (i < n) rowstart[i] = running + smem[threadIdx.x] - v;  // exclusive
        __syncthreads();
        if (threadIdx.x == 1023) running += smem[1023];
        __syncthreads();
    }
}

// counting-sort edges into row-contiguous segments; pre-resolve dis[c] and perm[c]
__global__ void reorder_k(const int* __restrict__ rows, const int* __restrict__ cols,
                          const int* __restrict__ rowstart, int* __restrict__ cursor,
                          const float* __restrict__ dis, const int* __restrict__ perm,
                          int* __restrict__ scols, int* __restrict__ scolp,
                          float* __restrict__ sdis, int e) {
    int i = blockIdx.x * blockDim.x + threadIdx.x;
    if (i >= e) return;
    int r = rows[i], c = cols[i];
    int pos = rowstart[r] + atomicAdd(&cursor[r], 1);
    scols[pos] = c;
    scolp[pos] = perm[c];   // corrupted gather index (feature-row permutation)
    sdis[pos]  = dis[c];    // norm factor of the col (graph-based, perm-independent)
}

// [n,64] @ [64,64]; W in LDS; 4 rows per 256-thread block, thread = (row,col)
__global__ void gemm64_k(const float* __restrict__ in, const float* __restrict__ W,
                         float* __restrict__ out, int n) {
    __shared__ float sW[D * D];
    for (int i = threadIdx.x; i < D * D; i += blockDim.x) sW[i] = W[i];
    __syncthreads();
    int r = blockIdx.x * (blockDim.x / D) + (threadIdx.x / D);
    int c = threadIdx.x & (D - 1);
    if (r >= n) return;
    const float* xr = in + (size_t)r * D;
    float acc = 0.f;
#pragma unroll
    for (int k = 0; k < D; ++k) acc = fmaf(xr[k], sW[k * D + c], acc);
    out[(size_t)r * D + c] = acc;
}

// Gather-only row aggregation: one wave per row, lane = feature.
// out[r] = dis[r] * (src[self]*dis[r]... folded) -- precisely:
// out[r] = dis[r] * ( dis[r]*src[sc] + sum_j sdis[j]*src[c_j] ) + b; optional PReLU.
__global__ void aggregate_k(const float* __restrict__ src, float* __restrict__ dst,
                            const float* __restrict__ dis,
                            const int* __restrict__ rowstart, const int* __restrict__ deg,
                            const int* __restrict__ scols, const float* __restrict__ sdis,
                            const float* __restrict__ bias, const float* __restrict__ prelu_a,
                            const int* __restrict__ perm, int n) {
    int lane = threadIdx.x & 63;
    int r = blockIdx.x * (blockDim.x >> 6) + (threadIdx.x >> 6);
    if (r >= n) return;
    int base = rowstart[r];
    int dg = deg[r];
    float dr = dis[r];
    int sc = perm ? perm[r] : r;                       // self-loop (corrupted in neg L1)
    float acc = dr * src[(size_t)sc * D + lane];
    int j = 0;
    for (; j + 4 <= dg; j += 4) {
        int   c0 = scols[base + j],     c1 = scols[base + j + 1];
        int   c2 = scols[base + j + 2], c3 = scols[base + j + 3];
        float n0 = sdis[base + j],      n1 = sdis[base + j + 1];
        float n2 = sdis[base + j + 2],  n3 = sdis[base + j + 3];
        float s0 = src[(size_t)c0 * D + lane];
        float s1 = src[(size_t)c1 * D + lane];
        float s2 = src[(size_t)c2 * D + lane];
        float s3 = src[(size_t)c3 * D + lane];
        acc = fmaf(n0, s0, acc); acc = fmaf(n1, s1, acc);
        acc = fmaf(n2, s2, acc); acc = fmaf(n3, s3, acc);
    }
    for (; j < dg; ++j) {
        int c = scols[base + j];
        float nc = sdis[base + j];
        acc = fmaf(nc, src[(size_t)c * D + lane], acc);
    }
    float v = fmaf(dr, acc, bias[lane]);
    if (prelu_a) { float a = *prelu_a; v = v >= 0.f ? v : a * v; }
    dst[(size_t)r * D + lane] = v;
}

__global__ void summary_partial_k(const float* __restrict__ pos, float* __restrict__ acc, int n) {
    int lane = threadIdx.x & 63;
    int wave = (blockIdx.x * blockDim.x + threadIdx.x) >> 6;
    int nw = (gridDim.x * blockDim.x) >> 6;
    float s = 0.f;
    for (int r = wave; r < n; r += nw) s += pos[(size_t)r * D + lane];
    atomicAdd(&acc[lane], s);
}

__global__ void summary_final_k(const float* __restrict__ acc, float* __restrict__ out, int n) {
    int f = threadIdx.x;
    if (f < D) {
        float m = acc[f] / (float)n;
        out[f] = 1.f / (1.f + expf(-m));
    }
}
} // namespace

extern "C" void kernel_launch(void* const* d_in, const int* in_sizes, int n_in,
                              void* d_out, int out_size, void* d_ws, size_t ws_size,
                              hipStream_t stream) {
    (void)in_sizes; (void)n_in; (void)out_size; (void)ws_size;
    const float* x       = (const float*)d_in[0];
    const int*   ei      = (const int*)  d_in[1];
    const int*   perm    = (const int*)  d_in[2];
    const float* W1      = (const float*)d_in[3];
    const float* b1      = (const float*)d_in[4];
    const float* prelu_a = (const float*)d_in[5];
    const float* W2      = (const float*)d_in[6];
    const float* b2      = (const float*)d_in[7];

    float* outP = (float*)d_out;
    float* outN = outP + (size_t)NN * D;
    float* outS = outN + (size_t)NN * D;

    const int* erows = ei;
    const int* ecols = ei + NE;

    char* ws = (char*)d_ws;
    size_t off = 0;
    auto alloc = [&](size_t bytes) {
        void* p = ws + off;
        off = (off + bytes + 255) & ~(size_t)255;
        return p;
    };
    int*   deg      = (int*)  alloc((size_t)NN * 4);
    float* dis      = (float*)alloc((size_t)NN * 4);
    int*   rowstart = (int*)  alloc((size_t)NN * 4);
    int*   cursor   = (int*)  alloc((size_t)NN * 4);
    int*   scols    = (int*)  alloc((size_t)NE * 4);
    int*   scolp    = (int*)  alloc((size_t)NE * 4);
    float* sdis     = (float*)alloc((size_t)NE * 4);
    float* xw       = (float*)alloc((size_t)NN * D * 4);
    float* aggP     = (float*)alloc((size_t)NN * D * 4);
    float* aggN     = (float*)alloc((size_t)NN * D * 4);
    float* acc      = (float*)alloc((size_t)D * 4);
    // ~91 MB total

    hipMemsetAsync(deg, 0, (size_t)NN * 4, stream);
    hipMemsetAsync(cursor, 0, (size_t)NN * 4, stream);
    hipMemsetAsync(acc, 0, (size_t)D * 4, stream);

    // graph preprocessing (once, reused by all 4 aggregation passes)
    count_deg_k<<<(NE + 255) / 256, 256, 0, stream>>>(erows, deg, NE);
    dis_k<<<(NN + 255) / 256, 256, 0, stream>>>(deg, dis, NN);
    scan_k<<<1, 1024, 0, stream>>>(deg, rowstart, NN);
    reorder_k<<<(NE + 255) / 256, 256, 0, stream>>>(erows, ecols, rowstart, cursor,
                                                    dis, perm, scols, scolp, sdis, NE);

    const int gemmBlocks = (NN + 3) / 4;
    const int aggBlocks  = (NN + 3) / 4;   // 4 waves/block, 1 row/wave

    // layer 1 (xw = x@W1 computed once; negative = permuted gather)
    gemm64_k<<<gemmBlocks, 256, 0, stream>>>(x, W1, xw, NN);
    aggregate_k<<<aggBlocks, 256, 0, stream>>>(xw, aggP, dis, rowstart, deg,
                                               scols, sdis, b1, prelu_a, nullptr, NN);
    aggregate_k<<<aggBlocks, 256, 0, stream>>>(xw, aggN, dis, rowstart, deg,
                                               scolp, sdis, b1, prelu_a, perm, NN);

    // layer 2 positive
    gemm64_k<<<gemmBlocks, 256, 0, stream>>>(aggP, W2, xw, NN);
    aggregate_k<<<aggBlocks, 256, 0, stream>>>(xw, outP, dis, rowstart, deg,
                                               scols, sdis, b2, nullptr, nullptr, NN);

    // layer 2 negative
    gemm64_k<<<gemmBlocks, 256, 0, stream>>>(aggN, W2, xw, NN);
    aggregate_k<<<aggBlocks, 256, 0, stream>>>(xw, outN, dis, rowstart, deg,
                                               scols, sdis, b2, nullptr, nullptr, NN);

    // summary = sigmoid(mean(positive, axis=0))
    summary_partial_k<<<256, 256, 0, stream>>>(outP, acc, NN);
    summary_final_k<<<1, 64, 0, stream>>>(acc, outS, NN);
}

// Round 3
// 603.571 us; speedup vs baseline: 2.4123x; 1.4426x over previous
//
#include <hip/hip_runtime.h>
#include <math.h>

namespace {
constexpr int NN = 100000;   // nodes
constexpr int NE = 1000000;  // edges
constexpr int D  = 64;       // feature dim
constexpr int SCAN_CHUNK = 2048;                 // 256 threads * 8
constexpr int NB = (NN + SCAN_CHUNK - 1) / SCAN_CHUNK;  // 49

__global__ void count_deg_k(const int* __restrict__ rows, int* __restrict__ deg, int e) {
    int i = blockIdx.x * blockDim.x + threadIdx.x;
    if (i < e) atomicAdd(&deg[rows[i]], 1);
}

__global__ void dis_k(const int* __restrict__ deg, float* __restrict__ dis, int n) {
    int i = blockIdx.x * blockDim.x + threadIdx.x;
    if (i < n) dis[i] = rsqrtf((float)(deg[i] + 1));  // +1 self-loop
}

// ---- 3-phase parallel exclusive scan of deg -> rowstart ----
__global__ void scan_partial_k(const int* __restrict__ deg, int* __restrict__ bsum, int n) {
    int base = blockIdx.x * SCAN_CHUNK + threadIdx.x * 8;
    int s = 0;
#pragma unroll
    for (int j = 0; j < 8; ++j) { int i = base + j; s += (i < n) ? deg[i] : 0; }
    for (int off = 32; off; off >>= 1) s += __shfl_down(s, off);
    __shared__ int ws[4];
    if ((threadIdx.x & 63) == 0) ws[threadIdx.x >> 6] = s;
    __syncthreads();
    if (threadIdx.x == 0) bsum[blockIdx.x] = ws[0] + ws[1] + ws[2] + ws[3];
}

__global__ void scan_bsums_k(const int* __restrict__ bsum, int* __restrict__ bpre, int nb) {
    __shared__ int sm[64];
    int v = ((int)threadIdx.x < nb) ? bsum[threadIdx.x] : 0;
    sm[threadIdx.x] = v;
    __syncthreads();
    for (int off = 1; off < 64; off <<= 1) {
        int t = ((int)threadIdx.x >= off) ? sm[threadIdx.x - off] : 0;
        __syncthreads();
        sm[threadIdx.x] += t;
        __syncthreads();
    }
    if ((int)threadIdx.x < nb) bpre[threadIdx.x] = sm[threadIdx.x] - v;  // exclusive
}

__global__ void scan_apply_k(const int* __restrict__ deg, const int* __restrict__ bpre,
                             int* __restrict__ rowstart, int n) {
    int tid = threadIdx.x;
    int base = blockIdx.x * SCAN_CHUNK + tid * 8;
    int v[8]; int s = 0;
#pragma unroll
    for (int j = 0; j < 8; ++j) { int i = base + j; v[j] = (i < n) ? deg[i] : 0; s += v[j]; }
    int lane = tid & 63, wid = tid >> 6;
    int sc = s;
    for (int off = 1; off < 64; off <<= 1) {
        int t = __shfl_up(sc, off);
        if (lane >= off) sc += t;
    }
    __shared__ int wsum[4];
    if (lane == 63) wsum[wid] = sc;
    __syncthreads();
    int wpre = 0;
    for (int w = 0; w < wid; ++w) wpre += wsum[w];
    int run = bpre[blockIdx.x] + wpre + sc - s;  // exclusive prefix of this thread
#pragma unroll
    for (int j = 0; j < 8; ++j) { int i = base + j; if (i < n) rowstart[i] = run; run += v[j]; }
}

// counting-sort edges into row-contiguous segments; pre-resolve dis[c] and perm[c]
__global__ void reorder_k(const int* __restrict__ rows, const int* __restrict__ cols,
                          const int* __restrict__ rowstart, int* __restrict__ cursor,
                          const float* __restrict__ dis, const int* __restrict__ perm,
                          int* __restrict__ scols, int* __restrict__ scolp,
                          float* __restrict__ sdis, int e) {
    int i = blockIdx.x * blockDim.x + threadIdx.x;
    if (i >= e) return;
    int r = rows[i], c = cols[i];
    int pos = rowstart[r] + atomicAdd(&cursor[r], 1);
    scols[pos] = c;
    scolp[pos] = perm[c];
    sdis[pos]  = dis[c];
}

// [n,64] @ [64,64]. Wave holds W[:,lane] in 64 VGPRs; row elements arrive as
// wave-uniform scalar loads; 64 v_fmac per row; no LDS. Safe in-place (each
// row read fully before its store, rows wave-exclusive).
constexpr int GEMM_RPW = 16;  // rows per wave
__global__ void gemm64_k(const float* in, const float* __restrict__ W, float* out, int n) {
    int lane = threadIdx.x & 63;
    int wave = (blockIdx.x * blockDim.x + threadIdx.x) >> 6;
    float wreg[D];
#pragma unroll
    for (int k = 0; k < D; ++k) wreg[k] = W[k * D + lane];
    int r0 = wave * GEMM_RPW;
    for (int ri = 0; ri < GEMM_RPW; ++ri) {
        int r = r0 + ri;
        if (r >= n) return;
        int rs = __builtin_amdgcn_readfirstlane(r);
        const float4* xr4 = (const float4*)(in + (size_t)rs * D);
        float acc = 0.f;
#pragma unroll
        for (int k4 = 0; k4 < D / 4; ++k4) {
            float4 xv = xr4[k4];
            acc = fmaf(xv.x, wreg[k4 * 4 + 0], acc);
            acc = fmaf(xv.y, wreg[k4 * 4 + 1], acc);
            acc = fmaf(xv.z, wreg[k4 * 4 + 2], acc);
            acc = fmaf(xv.w, wreg[k4 * 4 + 3], acc);
        }
        out[(size_t)rs * D + lane] = acc;
    }
}

// Dual gather-aggregate: one wave per row, lane = feature, P and N branches in
// one pass (shared index stream, 8 gathers in flight at unroll-4).
// out = dis[r]*(dis[selfX]*src[selfX] ... ) precisely:
//   accX = dis[r]*srcX[selfX] + sum_j sdis[j]*srcX[idxX[j]];  outX = dis[r]*accX + b
__global__ void agg_dual_k(const float* __restrict__ srcP, const float* __restrict__ srcN,
                           float* __restrict__ dstP, float* __restrict__ dstN,
                           const float* __restrict__ dis,
                           const int* __restrict__ rowstart, const int* __restrict__ deg,
                           const int* __restrict__ idxP, const int* __restrict__ idxN,
                           const float* __restrict__ sdis,
                           const float* __restrict__ bias, const float* __restrict__ prelu_a,
                           const int* __restrict__ perm, int n) {
    int lane = threadIdx.x & 63;
    int r = blockIdx.x * (blockDim.x >> 6) + (threadIdx.x >> 6);
    if (r >= n) return;
    int rs   = __builtin_amdgcn_readfirstlane(r);
    int base = __builtin_amdgcn_readfirstlane(rowstart[rs]);
    int dg   = __builtin_amdgcn_readfirstlane(deg[rs]);
    float dr = dis[rs];
    int selfN = perm ? perm[rs] : rs;
    float accP = dr * srcP[(size_t)rs * D + lane];
    float accN = dr * srcN[(size_t)selfN * D + lane];
    int j = 0;
    for (; j + 4 <= dg; j += 4) {
        int   cP0 = idxP[base+j],   cP1 = idxP[base+j+1], cP2 = idxP[base+j+2], cP3 = idxP[base+j+3];
        int   cN0 = idxN[base+j],   cN1 = idxN[base+j+1], cN2 = idxN[base+j+2], cN3 = idxN[base+j+3];
        float n0  = sdis[base+j],   n1  = sdis[base+j+1], n2  = sdis[base+j+2], n3  = sdis[base+j+3];
        float p0 = srcP[(size_t)cP0 * D + lane];
        float p1 = srcP[(size_t)cP1 * D + lane];
        float p2 = srcP[(size_t)cP2 * D + lane];
        float p3 = srcP[(size_t)cP3 * D + lane];
        float q0 = srcN[(size_t)cN0 * D + lane];
        float q1 = srcN[(size_t)cN1 * D + lane];
        float q2 = srcN[(size_t)cN2 * D + lane];
        float q3 = srcN[(size_t)cN3 * D + lane];
        accP = fmaf(n0, p0, accP); accP = fmaf(n1, p1, accP);
        accP = fmaf(n2, p2, accP); accP = fmaf(n3, p3, accP);
        accN = fmaf(n0, q0, accN); accN = fmaf(n1, q1, accN);
        accN = fmaf(n2, q2, accN); accN = fmaf(n3, q3, accN);
    }
    for (; j < dg; ++j) {
        int cP = idxP[base + j], cN = idxN[base + j];
        float nc = sdis[base + j];
        accP = fmaf(nc, srcP[(size_t)cP * D + lane], accP);
        accN = fmaf(nc, srcN[(size_t)cN * D + lane], accN);
    }
    float b = bias[lane];
    float vP = fmaf(dr, accP, b);
    float vN = fmaf(dr, accN, b);
    if (prelu_a) {
        float a = *prelu_a;
        vP = vP >= 0.f ? vP : a * vP;
        vN = vN >= 0.f ? vN : a * vN;
    }
    dstP[(size_t)rs * D + lane] = vP;
    dstN[(size_t)rs * D + lane] = vN;
}

__global__ void summary_partial_k(const float* __restrict__ pos, float* __restrict__ acc, int n) {
    int lane = threadIdx.x & 63;
    int wave = (blockIdx.x * blockDim.x + threadIdx.x) >> 6;
    int nw = (gridDim.x * blockDim.x) >> 6;
    float s = 0.f;
    for (int r = wave; r < n; r += nw) s += pos[(size_t)r * D + lane];
    atomicAdd(&acc[lane], s);
}

__global__ void summary_final_k(const float* __restrict__ acc, float* __restrict__ out, int n) {
    int f = threadIdx.x;
    if (f < D) {
        float m = acc[f] / (float)n;
        out[f] = 1.f / (1.f + expf(-m));
    }
}
} // namespace

extern "C" void kernel_launch(void* const* d_in, const int* in_sizes, int n_in,
                              void* d_out, int out_size, void* d_ws, size_t ws_size,
                              hipStream_t stream) {
    (void)in_sizes; (void)n_in; (void)out_size; (void)ws_size;
    const float* x       = (const float*)d_in[0];
    const int*   ei      = (const int*)  d_in[1];
    const int*   perm    = (const int*)  d_in[2];
    const float* W1      = (const float*)d_in[3];
    const float* b1      = (const float*)d_in[4];
    const float* prelu_a = (const float*)d_in[5];
    const float* W2      = (const float*)d_in[6];
    const float* b2      = (const float*)d_in[7];

    float* outP = (float*)d_out;
    float* outN = outP + (size_t)NN * D;
    float* outS = outN + (size_t)NN * D;

    const int* erows = ei;
    const int* ecols = ei + NE;

    char* ws = (char*)d_ws;
    size_t off = 0;
    auto alloc = [&](size_t bytes) {
        void* p = ws + off;
        off = (off + bytes + 255) & ~(size_t)255;
        return p;
    };
    int*   deg      = (int*)  alloc((size_t)NN * 4);
    float* dis      = (float*)alloc((size_t)NN * 4);
    int*   rowstart = (int*)  alloc((size_t)NN * 4);
    int*   cursor   = (int*)  alloc((size_t)NN * 4);
    int*   bsum     = (int*)  alloc(256);
    int*   bpre     = (int*)  alloc(256);
    int*   scols    = (int*)  alloc((size_t)NE * 4);
    int*   scolp    = (int*)  alloc((size_t)NE * 4);
    float* sdis     = (float*)alloc((size_t)NE * 4);
    float* xw       = (float*)alloc((size_t)NN * D * 4);
    float* aggP     = (float*)alloc((size_t)NN * D * 4);
    float* aggN     = (float*)alloc((size_t)NN * D * 4);
    float* acc      = (float*)alloc((size_t)D * 4);

    hipMemsetAsync(deg, 0, (size_t)NN * 4, stream);
    hipMemsetAsync(cursor, 0, (size_t)NN * 4, stream);
    hipMemsetAsync(acc, 0, (size_t)D * 4, stream);

    // graph preprocessing (reused by both layers and both branches)
    count_deg_k<<<(NE + 255) / 256, 256, 0, stream>>>(erows, deg, NE);
    dis_k<<<(NN + 255) / 256, 256, 0, stream>>>(deg, dis, NN);
    scan_partial_k<<<NB, 256, 0, stream>>>(deg, bsum, NN);
    scan_bsums_k<<<1, 64, 0, stream>>>(bsum, bpre, NB);
    scan_apply_k<<<NB, 256, 0, stream>>>(deg, bpre, rowstart, NN);
    reorder_k<<<(NE + 255) / 256, 256, 0, stream>>>(erows, ecols, rowstart, cursor,
                                                    dis, perm, scols, scolp, sdis, NE);

    const int gemmBlocks = (NN + GEMM_RPW * 4 - 1) / (GEMM_RPW * 4);
    const int aggBlocks  = (NN + 3) / 4;

    // layer 1: xw = x@W1 once; N branch = permuted gather from same table
    gemm64_k<<<gemmBlocks, 256, 0, stream>>>(x, W1, xw, NN);
    agg_dual_k<<<aggBlocks, 256, 0, stream>>>(xw, xw, aggP, aggN, dis, rowstart, deg,
                                              scols, scolp, sdis, b1, prelu_a, perm, NN);

    // layer 2: in-place gemms, then dual aggregate with shared index stream
    gemm64_k<<<gemmBlocks, 256, 0, stream>>>(aggP, W2, aggP, NN);
    gemm64_k<<<gemmBlocks, 256, 0, stream>>>(aggN, W2, aggN, NN);
    agg_dual_k<<<aggBlocks, 256, 0, stream>>>(aggP, aggN, outP, outN, dis, rowstart, deg,
                                              scols, scols, sdis, b2, nullptr, nullptr, NN);

    // summary = sigmoid(mean(positive, axis=0))
    summary_partial_k<<<256, 256, 0, stream>>>(outP, acc, NN);
    summary_final_k<<<1, 64, 0, stream>>>(acc, outS, NN);
}